// Round 3
// baseline (3135.850 us; speedup 1.0000x reference)
//
#include <hip/hip_runtime.h>
#include <cstdint>

typedef __attribute__((ext_vector_type(8))) short bf16x8;
typedef __attribute__((ext_vector_type(4))) float f32x4;
typedef unsigned short u16;
typedef unsigned int u32;
typedef unsigned long long u64;

#define T_STEPS 256
#define BATCH 64
#define HID 256
#define VOCAB 5000
#define KC 768            // 3*HID
#define NWG 16
#define HB 16             // HID / NWG
#define NPAD 5120         // 40*128
#define NTILES 5120       // 128 m-tiles * 40 n-tiles

// ---------- helpers ----------
__device__ __forceinline__ u16 f2bf(float x) {
  union { float f; u32 u; } v; v.f = x;
  u32 r = v.u + 0x7fffu + ((v.u >> 16) & 1u);
  return (u16)(r >> 16);
}
__device__ __forceinline__ float bf2f(u16 b) {
  union { float f; u32 u; } v; v.u = ((u32)b) << 16;
  return v.f;
}
__device__ __forceinline__ void load_lds16(const void* g, void* l) {
  __builtin_amdgcn_global_load_lds(
      (const __attribute__((address_space(1))) void*)g,
      (__attribute__((address_space(3))) void*)l, 16, 0, 0);
}
// Device-coherent 2B store: write-through to the coherent point (Infinity Cache).
__device__ __forceinline__ void st_u16_coh(u16* p, u16 v) {
  asm volatile("global_store_short %0, %1, off sc0 sc1" :: "v"(p), "v"((u32)v));
}
// Device-coherent 8B load (compiler-tracked vmcnt; pipelines across calls).
__device__ __forceinline__ u64 ld_u64_coh(const void* p) {
  return __hip_atomic_load((const u64*)p, __ATOMIC_RELAXED, __HIP_MEMORY_SCOPE_AGENT);
}
// fast sigmoid / tanh via v_exp_f32 + v_rcp_f32 (err ~1e-6, << bf16 rounding)
__device__ __forceinline__ float fsig(float x) {
  return __builtin_amdgcn_rcpf(1.f + __expf(-x));
}
__device__ __forceinline__ float ftanh(float x) {
  return 1.f - 2.f * __builtin_amdgcn_rcpf(1.f + __expf(2.f * x));
}

// ---------- prep: B' transposed [NPAD][KC] bf16, rows: [W_hi; W_hi; W_lo] ----------
__global__ __launch_bounds__(256) void prep_b(const float* __restrict__ Wd,
                                              u16* __restrict__ BT) {
  int gid = blockIdx.x * 256 + threadIdx.x;   // [0, 5120*96)
  int n = gid / 96;
  int k0 = (gid % 96) * 8;
  union { uint4 q; u16 s[8]; } o;
#pragma unroll
  for (int i = 0; i < 8; ++i) {
    int k = k0 + i;
    float x = 0.f;
    if (n < VOCAB) {
      int kk = (k < 512) ? (k & 255) : (k - 512);
      x = Wd[kk * VOCAB + n];
    }
    u16 hi = f2bf(x);
    o.s[i] = (k < 512) ? hi : f2bf(x - bf2f(hi));
  }
  *(uint4*)(BT + (size_t)n * KC + k0) = o.q;
}

// ---------- prep: h0 split hi/lo into A'-row-shaped scratch ----------
__global__ __launch_bounds__(256) void prep_h0(const float* __restrict__ h0,
                                               u16* __restrict__ H0S) {
  int i = blockIdx.x * 256 + threadIdx.x;  // 16384
  int b = i >> 8, j = i & 255;
  float x = h0[i];
  u16 hi = f2bf(x);
  u16 lo = f2bf(x - bf2f(hi));
  H0S[b * KC + j] = hi;
  H0S[b * KC + 256 + j] = lo;
}

// ---------- fused: blocks 0..15 = recurrence, blocks 16..255 = gemm workers ----------
// h-exchange is SELF-VALIDATING: each element is a tagged u64
// (epoch<<32 | hi<<16 | lo) in a parity-double-buffered Hex[2][64][256].
// Consumers batch-load their row's 64 tagged words and retry until all
// epochs == t — the successful load IS the synchronization (no acquire, no
// producer drain on the rec critical path). Per-wave "flags" are posted
// immediately (unordered) purely as a cheap spin target before the batch.
// Overwrite safety: row producers and row consumers share wave-id, so a
// wave reaching step t+2 proves all consumers of its rows finished step t
// (lag-2 invariant) before the parity buffer is overwritten.
// Workers gate on SEPARATE vmcnt(0)-ordered flags posted every 8th step.
__global__ __launch_bounds__(256, 1) void fused(
    const int* __restrict__ tokens, const float* __restrict__ h0,
    const float* __restrict__ ker, const float* __restrict__ rker,
    const float* __restrict__ bias,
    u16* Abuf, const u16* __restrict__ H0S,
    float* __restrict__ hlast, u32* flags, u64* Hex,
    const u16* __restrict__ BT, const float* __restrict__ bd,
    float* __restrict__ out) {
  __shared__ u16 As[128 * 32];
  __shared__ u16 Bs[128 * 32];
  __shared__ u32 stile;

  const int tid = threadIdx.x;

  if (blockIdx.x < NWG) {
    // ================= recurrence path =================
    const int g = blockIdx.x;
    const int w = tid >> 6;        // wave id = m-tile
    const int l = tid & 63;
    const int lm = l & 15;
    const int lq = l >> 4;

    int cmap[3]; float brec[3], bin[3];
#pragma unroll
    for (int nt = 0; nt < 3; ++nt) {
      cmap[nt] = nt * 256 + g * HB + lm;
      bin[nt]  = bias[cmap[nt]];
      brec[nt] = bias[KC + cmap[nt]];
    }

    // Step-invariant B-fragments: rk_slice hi/lo, B[k][n]: n=lane&15, k=quad*8+j
    bf16x8 Bhi[3][8], Blo[3][8];
#pragma unroll
    for (int nt = 0; nt < 3; ++nt)
#pragma unroll
      for (int kb = 0; kb < 8; ++kb) {
        union { bf16x8 v; u16 s[8]; } uh, ul;
#pragma unroll
        for (int jj = 0; jj < 8; ++jj) {
          int k = kb * 32 + lq * 8 + jj;
          float x = rker[k * KC + cmap[nt]];
          u16 hi = f2bf(x);
          uh.s[jj] = hi;
          ul.s[jj] = f2bf(x - bf2f(hi));
        }
        Bhi[nt][kb] = uh.v; Blo[nt][kb] = ul.v;
      }

    // own h in f32, D-layout: row b = 16w + lq*4 + r, col j = g*HB + lm
    float hown[4];
#pragma unroll
    for (int r = 0; r < 4; ++r)
      hown[r] = h0[(16 * w + lq * 4 + r) * HID + g * HB + lm];

    const int rowloc = 16 * w + lm;   // A-frag row (m = lane&15)
    u32* wflags = flags + 2048;       // vmcnt-ordered, for gemm workers

    int ntok[4];
#pragma unroll
    for (int r = 0; r < 4; ++r)
      ntok[r] = tokens[(16 * w + lq * 4 + r) * T_STEPS];

    for (int t = 0; t < T_STEPS; ++t) {
      int ctok[4];
#pragma unroll
      for (int r = 0; r < 4; ++r) ctok[r] = ntok[r];
      if (t + 1 < T_STEPS) {
#pragma unroll
        for (int r = 0; r < 4; ++r)
          ntok[r] = tokens[(16 * w + lq * 4 + r) * T_STEPS + t + 1];
      }

      // embedding gathers — independent of the exchange, issued first
      float mx[3][4];
#pragma unroll
      for (int r = 0; r < 4; ++r) {
#pragma unroll
        for (int nt = 0; nt < 3; ++nt)
          mx[nt][r] = ker[(size_t)ctok[r] * KC + cmap[nt]] + bin[nt];
      }

      bf16x8 Ahi[8], Alo[8];
      if (t == 0) {
        const u16* hrow = H0S + (size_t)rowloc * KC;
#pragma unroll
        for (int kb = 0; kb < 8; ++kb) {
          union { uint4 q; bf16x8 v; } a0, a1;
          a0.q = *(const uint4*)(hrow + kb * 32 + lq * 8);
          a1.q = *(const uint4*)(hrow + 256 + kb * 32 + lq * 8);
          Ahi[kb] = a0.v; Alo[kb] = a1.v;
        }
      } else {
        const u32 tt = (u32)t;
        // cheap spin on unordered per-wave hint flags
        int guard = 0;
        for (;;) {
          u32 v = __hip_atomic_load(&flags[l * 32], __ATOMIC_RELAXED,
                                    __HIP_MEMORY_SCOPE_AGENT);
          if (__all((int)(v >= tt))) break;
          if (++guard > (1 << 24)) break;   // safety valve (never expected)
          __builtin_amdgcn_s_sleep(1);
        }
        // self-validating batch: load 64 tagged words, verify epoch == t
        const u64* Hrow = Hex + (((size_t)((t - 1) & 1)) << 14)
                              + (size_t)rowloc * 256;
        union U64 { u64 d; u32 u[2]; u16 s[4]; } q[8][8];
        int g2 = 0;
        for (;;) {
#pragma unroll
          for (int kb = 0; kb < 8; ++kb)
#pragma unroll
            for (int jj = 0; jj < 8; ++jj)
              q[kb][jj].d = ld_u64_coh(Hrow + kb * 32 + lq * 8 + jj);
          u32 bad = 0;
#pragma unroll
          for (int kb = 0; kb < 8; ++kb)
#pragma unroll
            for (int jj = 0; jj < 8; ++jj)
              bad |= q[kb][jj].u[1] ^ tt;
          if (__all(bad == 0)) break;
          if (++g2 > (1 << 20)) break;      // safety valve
          __builtin_amdgcn_s_sleep(1);
        }
#pragma unroll
        for (int kb = 0; kb < 8; ++kb) {
          union { bf16x8 v; u16 s[8]; } uh, ul;
#pragma unroll
          for (int jj = 0; jj < 8; ++jj) {
            uh.s[jj] = q[kb][jj].s[1];
            ul.s[jj] = q[kb][jj].s[0];
          }
          Ahi[kb] = uh.v; Alo[kb] = ul.v;
        }
      }

      f32x4 acc[3];
#pragma unroll
      for (int nt = 0; nt < 3; ++nt)
        acc[nt] = (f32x4){brec[nt], brec[nt], brec[nt], brec[nt]};

#pragma unroll
      for (int kb = 0; kb < 8; ++kb) {
#pragma unroll
        for (int nt = 0; nt < 3; ++nt) {
          acc[nt] = __builtin_amdgcn_mfma_f32_16x16x32_bf16(Ahi[kb], Bhi[nt][kb], acc[nt], 0, 0, 0);
          acc[nt] = __builtin_amdgcn_mfma_f32_16x16x32_bf16(Alo[kb], Bhi[nt][kb], acc[nt], 0, 0, 0);
          acc[nt] = __builtin_amdgcn_mfma_f32_16x16x32_bf16(Ahi[kb], Blo[nt][kb], acc[nt], 0, 0, 0);
        }
      }

      u64* HexT = Hex + (((size_t)(t & 1)) << 14);
#pragma unroll
      for (int r = 0; r < 4; ++r) {
        float z  = fsig(acc[0][r] + mx[0][r]);
        float rr = fsig(acc[1][r] + mx[1][r]);
        float cd = ftanh(mx[2][r] + rr * acc[2][r]);   // reset_after candidate
        float hn = z * hown[r] + (1.f - z) * cd;
        hown[r] = hn;
        u16 hi = f2bf(hn);
        u16 lo = f2bf(hn - bf2f(hi));
        int b = 16 * w + lq * 4 + r;
        // Abuf for the output GEMM (workers + coherence via wflags)
        u16* orow = Abuf + (size_t)(t * BATCH + b) * KC;
        st_u16_coh(orow + g * HB + lm, hi);
        st_u16_coh(orow + 256 + g * HB + lm, lo);
        st_u16_coh(orow + 512 + g * HB + lm, hi);
        // tagged self-validating exchange word
        u64 tw = ((u64)(u32)(t + 1) << 32) | ((u32)hi << 16) | (u32)lo;
        __hip_atomic_store(HexT + (size_t)b * 256 + g * HB + lm, tw,
                           __ATOMIC_RELAXED, __HIP_MEMORY_SCOPE_AGENT);
      }

      // unordered hint flag — no drain; epoch check handles any race
      if (l == 0)
        __hip_atomic_store(&flags[(g * 4 + w) * 32], (u32)(t + 1),
                           __ATOMIC_RELAXED, __HIP_MEMORY_SCOPE_AGENT);
      // ordered worker flag every 8th step only
      if ((t & 7) == 7) {
        asm volatile("s_waitcnt vmcnt(0)" ::: "memory");
        if (l == 0)
          __hip_atomic_store(&wflags[(g * 4 + w) * 32], (u32)(t + 1),
                             __ATOMIC_RELAXED, __HIP_MEMORY_SCOPE_AGENT);
      }
    }

#pragma unroll
    for (int r = 0; r < 4; ++r) {
      int b = 16 * w + lq * 4 + r;
      hlast[b * HID + g * HB + lm] = hown[r];
    }
    return;
  }

  // ===================== gemm worker path =====================
  u32* counter = flags + 6144;     // own line, far from flag/wflag lines
  u32* wflags = flags + 2048;
  const int w = tid >> 6, l = tid & 63;
  const int lm = l & 15, lq = l >> 4;
  const int wm = w & 1, wn = w >> 1;

  for (;;) {
    __syncthreads();   // protect As/Bs + stile from the previous tile
    if (tid == 0)
      stile = __hip_atomic_fetch_add(counter, 1u, __ATOMIC_RELAXED,
                                     __HIP_MEMORY_SCOPE_AGENT);
    __syncthreads();
    const u32 tile = stile;
    if (tile >= NTILES) break;
    const int mi = (int)(tile / 40);
    const int ni = (int)(tile % 40);
    const int m0 = mi * 128;
    const int n0 = ni * 128;

    // gate: rows m0..m0+127 = time steps {2mi, 2mi+1}; wflags hold multiples of 8
    if (tid < 64) {
      const u32 need = (u32)(2 * mi + 2);
      int guard = 0;
      for (;;) {
        u32 v = __hip_atomic_load(&wflags[tid * 32], __ATOMIC_RELAXED,
                                  __HIP_MEMORY_SCOPE_AGENT);
        if (__all((int)(v >= need))) break;
        if (++guard > (1 << 22)) break;   // safety valve
        __builtin_amdgcn_s_sleep(64);
      }
    }
    __syncthreads();

    const int tr = tid >> 2;        // row within 64-row group
    const int tc = (tid & 3) * 8;   // ushort col offset

    f32x4 acc[4][4] = {};

    for (int kb = 0; kb < 24; ++kb) {
      if (kb) __syncthreads();
#pragma unroll
      for (int j = 0; j < 2; ++j) {
        load_lds16(Abuf + (size_t)(m0 + j * 64 + tr) * KC + kb * 32 + tc,
                   As + j * 2048 + w * 512);
        load_lds16(BT   + (size_t)(n0 + j * 64 + tr) * KC + kb * 32 + tc,
                   Bs + j * 2048 + w * 512);
      }
      __syncthreads();

      bf16x8 af[4], bfr[4];
#pragma unroll
      for (int mi2 = 0; mi2 < 4; ++mi2)
        af[mi2] = *(const bf16x8*)(As + (wm * 64 + mi2 * 16 + lm) * 32 + lq * 8);
#pragma unroll
      for (int ni2 = 0; ni2 < 4; ++ni2)
        bfr[ni2] = *(const bf16x8*)(Bs + (wn * 64 + ni2 * 16 + lm) * 32 + lq * 8);
#pragma unroll
      for (int mi2 = 0; mi2 < 4; ++mi2)
#pragma unroll
        for (int ni2 = 0; ni2 < 4; ++ni2)
          acc[mi2][ni2] = __builtin_amdgcn_mfma_f32_16x16x32_bf16(af[mi2], bfr[ni2], acc[mi2][ni2], 0, 0, 0);
    }

#pragma unroll
    for (int ni2 = 0; ni2 < 4; ++ni2) {
      int n = n0 + wn * 64 + ni2 * 16 + lm;
      float bdv = (n < VOCAB) ? bd[n] : 0.f;
#pragma unroll
      for (int mi2 = 0; mi2 < 4; ++mi2) {
#pragma unroll
        for (int r = 0; r < 4; ++r) {
          int m = m0 + wm * 64 + mi2 * 16 + lq * 4 + r;
          if (n < VOCAB) out[(size_t)m * VOCAB + n] = acc[mi2][ni2][r] + bdv;
        }
      }
    }
  }
}

// ---------- launch ----------
extern "C" void kernel_launch(void* const* d_in, const int* in_sizes, int n_in,
                              void* d_out, int out_size, void* d_ws, size_t ws_size,
                              hipStream_t stream) {
  const int*   tokens = (const int*)d_in[0];
  const float* h0     = (const float*)d_in[1];
  const float* ker    = (const float*)d_in[2];
  const float* rker   = (const float*)d_in[3];
  const float* bias   = (const float*)d_in[4];
  const float* Wd     = (const float*)d_in[5];
  const float* bd     = (const float*)d_in[6];
  float* out = (float*)d_out;
  char* ws = (char*)d_ws;

  // workspace layout (bytes)
  u16* Abuf  = (u16*)(ws);              // 16384*768*2 = 25,165,824
  u16* BT    = (u16*)(ws + 25165824);   //  5120*768*2 =  7,864,320
  u16* H0S   = (u16*)(ws + 33030144);   //    64*768*2 =     98,304
  u32* flags = (u32*)(ws + 33128448);   //  hint flags + wflags + counter = 32,768
  u64* Hex   = (u64*)(ws + 33161216);   //  2*64*256*8 = 262,144

  hipMemsetAsync(flags, 0, 32768, stream);
  prep_b<<<1920, 256, 0, stream>>>(Wd, BT);
  prep_h0<<<64, 256, 0, stream>>>(h0, H0S);
  fused<<<256, 256, 0, stream>>>(tokens, h0, ker, rker, bias, Abuf, H0S,
                                 out + (size_t)16384 * VOCAB, flags, Hex,
                                 BT, bd, out);
}

// Round 5
// 2053.276 us; speedup vs baseline: 1.5272x; 1.5272x over previous
//
#include <hip/hip_runtime.h>
#include <cstdint>

typedef __attribute__((ext_vector_type(8))) short bf16x8;
typedef __attribute__((ext_vector_type(4))) float f32x4;
typedef unsigned short u16;
typedef unsigned int u32;
typedef unsigned long long u64;

#define T_STEPS 256
#define BATCH 64
#define HID 256
#define VOCAB 5000
#define KC 768            // 3*HID
#define NWG 16
#define HB 16             // HID / NWG
#define NPAD 5120         // 40*128
#define NTILES 5120       // 128 m-tiles * 40 n-tiles

// flags region layout (u32 indices)
#define FI_CNT   0        // 4 drained per-class counters, 256B apart
#define FI_TILE  1024     // worker tile queue counter

// ---------- helpers ----------
__device__ __forceinline__ u16 f2bf(float x) {
  union { float f; u32 u; } v; v.f = x;
  u32 r = v.u + 0x7fffu + ((v.u >> 16) & 1u);
  return (u16)(r >> 16);
}
__device__ __forceinline__ float bf2f(u16 b) {
  union { float f; u32 u; } v; v.u = ((u32)b) << 16;
  return v.f;
}
__device__ __forceinline__ void load_lds16(const void* g, void* l) {
  __builtin_amdgcn_global_load_lds(
      (const __attribute__((address_space(1))) void*)g,
      (__attribute__((address_space(3))) void*)l, 16, 0, 0);
}
// Device-coherent stores: write-through to the coherent point (Infinity Cache).
__device__ __forceinline__ void st_u16_coh(u16* p, u16 v) {
  asm volatile("global_store_short %0, %1, off sc0 sc1" :: "v"(p), "v"((u32)v));
}
__device__ __forceinline__ void st_u32_coh(u32* p, u32 v) {
  asm volatile("global_store_dword %0, %1, off sc0 sc1" :: "v"(p), "v"(v));
}
// Device-coherent 8B load (compiler-tracked vmcnt; pipelines across calls).
__device__ __forceinline__ u64 ld_u64_coh(const void* p) {
  return __hip_atomic_load((const u64*)p, __ATOMIC_RELAXED, __HIP_MEMORY_SCOPE_AGENT);
}
// fast sigmoid / tanh via v_exp_f32 + v_rcp_f32 (err ~1e-6, << bf16 rounding)
__device__ __forceinline__ float fsig(float x) {
  return __builtin_amdgcn_rcpf(1.f + __expf(-x));
}
__device__ __forceinline__ float ftanh(float x) {
  return 1.f - 2.f * __builtin_amdgcn_rcpf(1.f + __expf(2.f * x));
}

// ---------- prep: B' transposed [NPAD][KC] bf16, rows: [W_hi; W_hi; W_lo] ----------
__global__ __launch_bounds__(256) void prep_b(const float* __restrict__ Wd,
                                              u16* __restrict__ BT) {
  int gid = blockIdx.x * 256 + threadIdx.x;   // [0, 5120*96)
  int n = gid / 96;
  int k0 = (gid % 96) * 8;
  union { uint4 q; u16 s[8]; } o;
#pragma unroll
  for (int i = 0; i < 8; ++i) {
    int k = k0 + i;
    float x = 0.f;
    if (n < VOCAB) {
      int kk = (k < 512) ? (k & 255) : (k - 512);
      x = Wd[kk * VOCAB + n];
    }
    u16 hi = f2bf(x);
    o.s[i] = (k < 512) ? hi : f2bf(x - bf2f(hi));
  }
  *(uint4*)(BT + (size_t)n * KC + k0) = o.q;
}

// ---------- prep: h0 split hi/lo into A'-row-shaped scratch ----------
__global__ __launch_bounds__(256) void prep_h0(const float* __restrict__ h0,
                                               u16* __restrict__ H0S) {
  int i = blockIdx.x * 256 + threadIdx.x;  // 16384
  int b = i >> 8, j = i & 255;
  float x = h0[i];
  u16 hi = f2bf(x);
  u16 lo = f2bf(x - bf2f(hi));
  H0S[b * KC + j] = hi;
  H0S[b * KC + 256 + j] = lo;
}

// ---------- fused: blocks 0..15 = recurrence, blocks 16..255 = gemm workers ----------
// Exchange protocol (round 5 — r1-proven drained protocol, cheap spin):
//  * Hex u32[2][64][256] (hi<<16|lo), parity double-buffered, L3-resident.
//  * 4 independent wave-classes by wave-id w. Class-w rows [16w,16w+16) are
//    produced AND consumed exclusively by the 16 class-w waves (one per WG).
//  * Producer (per wave, per step): sc0|sc1 stores (Abuf + Hex) ->
//    s_waitcnt vmcnt(0) (stores acked at coherent point) -> lane0
//    fetch_add(cnt[w]). Counter observed ==> data globally visible.
//  * Consumer at step t: spin on ONE line until cnt[w] >= 16*t (all class
//    peers finished step t-1), then direct sc0|sc1 data loads. No tags,
//    no retry, no syncthreads, no acquire fence (loads bypass L1/L2).
//  * Parity overwrite safety: wave at step t+1 saw cnt >= 16(t+1) ==> every
//    peer finished step t ==> consumed the parity buffer being overwritten.
//  * Workers gate on the same 4 drained counters (drain covers Abuf stores):
//    tile row-block mi needs cnt[c] >= 16*(2mi+2) for all c.
__global__ __launch_bounds__(256, 1) void fused(
    const int* __restrict__ tokens, const float* __restrict__ h0,
    const float* __restrict__ ker, const float* __restrict__ rker,
    const float* __restrict__ bias,
    u16* Abuf, const u16* __restrict__ H0S,
    float* __restrict__ hlast, u32* flags, u32* Hex,
    const u16* __restrict__ BT, const float* __restrict__ bd,
    float* __restrict__ out) {
  __shared__ u16 As[128 * 32];
  __shared__ u16 Bs[128 * 32];
  __shared__ u32 stile;

  const int tid = threadIdx.x;

  if (blockIdx.x < NWG) {
    // ================= recurrence path =================
    const int g = blockIdx.x;
    const int w = tid >> 6;        // wave id = m-tile = class id
    const int l = tid & 63;
    const int lm = l & 15;
    const int lq = l >> 4;

    int cmap[3]; float brec[3], bin[3];
#pragma unroll
    for (int nt = 0; nt < 3; ++nt) {
      cmap[nt] = nt * 256 + g * HB + lm;
      bin[nt]  = bias[cmap[nt]];
      brec[nt] = bias[KC + cmap[nt]];
    }

    // Step-invariant B-fragments: rk_slice hi/lo, B[k][n]: n=lane&15, k=quad*8+j
    bf16x8 Bhi[3][8], Blo[3][8];
#pragma unroll
    for (int nt = 0; nt < 3; ++nt)
#pragma unroll
      for (int kb = 0; kb < 8; ++kb) {
        union { bf16x8 v; u16 s[8]; } uh, ul;
#pragma unroll
        for (int jj = 0; jj < 8; ++jj) {
          int k = kb * 32 + lq * 8 + jj;
          float x = rker[k * KC + cmap[nt]];
          u16 hi = f2bf(x);
          uh.s[jj] = hi;
          ul.s[jj] = f2bf(x - bf2f(hi));
        }
        Bhi[nt][kb] = uh.v; Blo[nt][kb] = ul.v;
      }

    // own h in f32, D-layout: row b = 16w + lq*4 + r, col j = g*HB + lm
    float hown[4];
#pragma unroll
    for (int r = 0; r < 4; ++r)
      hown[r] = h0[(16 * w + lq * 4 + r) * HID + g * HB + lm];

    const int rowloc = 16 * w + lm;   // A-frag row (m = lane&15)
    u32* cnt = &flags[FI_CNT + w * 64];   // drained per-class counter

    int ntok[4];
#pragma unroll
    for (int r = 0; r < 4; ++r)
      ntok[r] = tokens[(16 * w + lq * 4 + r) * T_STEPS];

    for (int t = 0; t < T_STEPS; ++t) {
      int ctok[4];
#pragma unroll
      for (int r = 0; r < 4; ++r) ctok[r] = ntok[r];
      if (t + 1 < T_STEPS) {
#pragma unroll
        for (int r = 0; r < 4; ++r)
          ntok[r] = tokens[(16 * w + lq * 4 + r) * T_STEPS + t + 1];
      }

      // embedding gathers — independent of the exchange, issued first
      float mx[3][4];
#pragma unroll
      for (int r = 0; r < 4; ++r) {
#pragma unroll
        for (int nt = 0; nt < 3; ++nt)
          mx[nt][r] = ker[(size_t)ctok[r] * KC + cmap[nt]] + bin[nt];
      }

      bf16x8 Ahi[8], Alo[8];
      if (t == 0) {
        const u16* hrow = H0S + (size_t)rowloc * KC;
#pragma unroll
        for (int kb = 0; kb < 8; ++kb) {
          union { uint4 q; bf16x8 v; } a0, a1;
          a0.q = *(const uint4*)(hrow + kb * 32 + lq * 8);
          a1.q = *(const uint4*)(hrow + 256 + kb * 32 + lq * 8);
          Ahi[kb] = a0.v; Alo[kb] = a1.v;
        }
      } else {
        // spin on ONE coherent line: all class peers finished step t-1
        const u32 needc = 16u * (u32)t;
        int guard = 0;
        for (;;) {
          u32 v = __hip_atomic_load(cnt, __ATOMIC_RELAXED,
                                    __HIP_MEMORY_SCOPE_AGENT);
          if (v >= needc) break;
          if (++guard > (1 << 22)) break;   // safety valve (never expected)
          __builtin_amdgcn_s_sleep(1);
        }
        // direct coherent loads; per-kb streaming (no bulk register block)
        const u32* Hrow = Hex + (((size_t)((t - 1) & 1)) << 14)
                              + (size_t)rowloc * 256;
#pragma unroll
        for (int kb = 0; kb < 8; ++kb) {
          union { u64 d[4]; u16 s[16]; } q;
          const u32* p = Hrow + kb * 32 + lq * 8;
          q.d[0] = ld_u64_coh(p);
          q.d[1] = ld_u64_coh(p + 2);
          q.d[2] = ld_u64_coh(p + 4);
          q.d[3] = ld_u64_coh(p + 6);
          union { bf16x8 v; u16 s[8]; } uh, ul;
#pragma unroll
          for (int j = 0; j < 8; ++j) {
            ul.s[j] = q.s[2 * j];       // low u16  = lo
            uh.s[j] = q.s[2 * j + 1];   // high u16 = hi
          }
          Ahi[kb] = uh.v; Alo[kb] = ul.v;
        }
      }

      f32x4 acc[3];
#pragma unroll
      for (int nt = 0; nt < 3; ++nt)
        acc[nt] = (f32x4){brec[nt], brec[nt], brec[nt], brec[nt]};

#pragma unroll
      for (int kb = 0; kb < 8; ++kb) {
#pragma unroll
        for (int nt = 0; nt < 3; ++nt) {
          acc[nt] = __builtin_amdgcn_mfma_f32_16x16x32_bf16(Ahi[kb], Bhi[nt][kb], acc[nt], 0, 0, 0);
          acc[nt] = __builtin_amdgcn_mfma_f32_16x16x32_bf16(Alo[kb], Bhi[nt][kb], acc[nt], 0, 0, 0);
          acc[nt] = __builtin_amdgcn_mfma_f32_16x16x32_bf16(Ahi[kb], Blo[nt][kb], acc[nt], 0, 0, 0);
        }
      }

      u32* HexT = Hex + (((size_t)(t & 1)) << 14);
#pragma unroll
      for (int r = 0; r < 4; ++r) {
        float z  = fsig(acc[0][r] + mx[0][r]);
        float rr = fsig(acc[1][r] + mx[1][r]);
        float cd = ftanh(mx[2][r] + rr * acc[2][r]);   // reset_after candidate
        float hn = z * hown[r] + (1.f - z) * cd;
        hown[r] = hn;
        u16 hi = f2bf(hn);
        u16 lo = f2bf(hn - bf2f(hi));
        int b = 16 * w + lq * 4 + r;
        // Abuf for the output GEMM (visibility via drained counters)
        u16* orow = Abuf + (size_t)(t * BATCH + b) * KC;
        st_u16_coh(orow + g * HB + lm, hi);
        st_u16_coh(orow + 256 + g * HB + lm, lo);
        st_u16_coh(orow + 512 + g * HB + lm, hi);
        // compact exchange word
        st_u32_coh(HexT + (size_t)b * 256 + g * HB + lm,
                   ((u32)hi << 16) | (u32)lo);
      }

      // drained release: stores acked at coherent point, THEN bump counter
      asm volatile("s_waitcnt vmcnt(0)" ::: "memory");
      if (l == 0)
        __hip_atomic_fetch_add(cnt, 1u, __ATOMIC_RELAXED,
                               __HIP_MEMORY_SCOPE_AGENT);
      asm volatile("" ::: "memory");
    }

#pragma unroll
    for (int r = 0; r < 4; ++r) {
      int b = 16 * w + lq * 4 + r;
      hlast[b * HID + g * HB + lm] = hown[r];
    }
    return;
  }

  // ===================== gemm worker path =====================
  u32* counter = &flags[FI_TILE];
  const int w = tid >> 6, l = tid & 63;
  const int lm = l & 15, lq = l >> 4;
  const int wm = w & 1, wn = w >> 1;

  for (;;) {
    __syncthreads();   // protect As/Bs + stile from the previous tile
    if (tid == 0)
      stile = __hip_atomic_fetch_add(counter, 1u, __ATOMIC_RELAXED,
                                     __HIP_MEMORY_SCOPE_AGENT);
    __syncthreads();
    const u32 tile = stile;
    if (tile >= NTILES) break;
    const int mi = (int)(tile / 40);
    const int ni = (int)(tile % 40);
    const int m0 = mi * 128;
    const int n0 = ni * 128;

    // gate: rows m0..m0+127 = steps {2mi, 2mi+1}; counters are drained, so
    // cnt[c] >= 16*(2mi+2) for all 4 classes ==> Abuf rows visible.
    if (tid == 0) {
      const u32 needw = 16u * (u32)(2 * mi + 2);
      int guard = 0;
      for (;;) {
        u32 ok = 1;
#pragma unroll
        for (int c = 0; c < 4; ++c) {
          u32 v = __hip_atomic_load(&flags[FI_CNT + c * 64], __ATOMIC_RELAXED,
                                    __HIP_MEMORY_SCOPE_AGENT);
          ok &= (u32)(v >= needw);
        }
        if (ok) break;
        if (++guard > (1 << 22)) break;   // safety valve
        __builtin_amdgcn_s_sleep(32);
      }
    }
    __syncthreads();

    const int tr = tid >> 2;        // row within 64-row group
    const int tc = (tid & 3) * 8;   // ushort col offset

    f32x4 acc[4][4] = {};

    for (int kb = 0; kb < 24; ++kb) {
      if (kb) __syncthreads();
#pragma unroll
      for (int j = 0; j < 2; ++j) {
        load_lds16(Abuf + (size_t)(m0 + j * 64 + tr) * KC + kb * 32 + tc,
                   As + j * 2048 + w * 512);
        load_lds16(BT   + (size_t)(n0 + j * 64 + tr) * KC + kb * 32 + tc,
                   Bs + j * 2048 + w * 512);
      }
      __syncthreads();

      bf16x8 af[4], bfr[4];
#pragma unroll
      for (int mi2 = 0; mi2 < 4; ++mi2)
        af[mi2] = *(const bf16x8*)(As + (wm * 64 + mi2 * 16 + lm) * 32 + lq * 8);
#pragma unroll
      for (int ni2 = 0; ni2 < 4; ++ni2)
        bfr[ni2] = *(const bf16x8*)(Bs + (wn * 64 + ni2 * 16 + lm) * 32 + lq * 8);
#pragma unroll
      for (int mi2 = 0; mi2 < 4; ++mi2)
#pragma unroll
        for (int ni2 = 0; ni2 < 4; ++ni2)
          acc[mi2][ni2] = __builtin_amdgcn_mfma_f32_16x16x32_bf16(af[mi2], bfr[ni2], acc[mi2][ni2], 0, 0, 0);
    }

#pragma unroll
    for (int ni2 = 0; ni2 < 4; ++ni2) {
      int n = n0 + wn * 64 + ni2 * 16 + lm;
      float bdv = (n < VOCAB) ? bd[n] : 0.f;
#pragma unroll
      for (int mi2 = 0; mi2 < 4; ++mi2) {
#pragma unroll
        for (int r = 0; r < 4; ++r) {
          int m = m0 + wm * 64 + mi2 * 16 + lq * 4 + r;
          if (n < VOCAB) out[(size_t)m * VOCAB + n] = acc[mi2][ni2][r] + bdv;
        }
      }
    }
  }
}

// ---------- launch ----------
extern "C" void kernel_launch(void* const* d_in, const int* in_sizes, int n_in,
                              void* d_out, int out_size, void* d_ws, size_t ws_size,
                              hipStream_t stream) {
  const int*   tokens = (const int*)d_in[0];
  const float* h0     = (const float*)d_in[1];
  const float* ker    = (const float*)d_in[2];
  const float* rker   = (const float*)d_in[3];
  const float* bias   = (const float*)d_in[4];
  const float* Wd     = (const float*)d_in[5];
  const float* bd     = (const float*)d_in[6];
  float* out = (float*)d_out;
  char* ws = (char*)d_ws;

  // workspace layout (bytes)
  u16* Abuf  = (u16*)(ws);              // 16384*768*2 = 25,165,824
  u16* BT    = (u16*)(ws + 25165824);   //  5120*768*2 =  7,864,320
  u16* H0S   = (u16*)(ws + 33030144);   //    64*768*2 =     98,304
  u32* flags = (u32*)(ws + 33128448);   //  counters region = 8,192
  u32* Hex   = (u32*)(ws + 33136640);   //  2*64*256*4 = 131,072

  hipMemsetAsync(flags, 0, 8192, stream);
  prep_b<<<1920, 256, 0, stream>>>(Wd, BT);
  prep_h0<<<64, 256, 0, stream>>>(h0, H0S);
  fused<<<256, 256, 0, stream>>>(tokens, h0, ker, rker, bias, Abuf, H0S,
                                 out + (size_t)16384 * VOCAB, flags, Hex,
                                 BT, bd, out);
}